// Round 1
// baseline (2188.666 us; speedup 1.0000x reference)
//
#include <hip/hip_runtime.h>
#include <hip/hip_bf16.h>
#include <cstdint>
#include <math.h>

using bf16 = __hip_bfloat16;
typedef __attribute__((ext_vector_type(4))) float f32x4;
typedef __attribute__((ext_vector_type(8))) short s16x8;

#define AS3(p) ((__attribute__((address_space(3))) void *)(p))
#define AS1(p) ((const __attribute__((address_space(1))) void *)(p))

static constexpr int Himg = 256, Wimg = 256, Bimg = 4;
static constexpr int HWimg = Himg * Wimg;
static constexpr int Ttok = Bimg * HWimg;   // 262144 tokens

__device__ __forceinline__ void gld16(bf16* lds, const bf16* g) {
  __builtin_amdgcn_global_load_lds(AS1(g), AS3(lds), 16, 0, 0);
}

__device__ __forceinline__ float b2f(unsigned short u) {
  unsigned int v = ((unsigned int)u) << 16;
  float f; __builtin_memcpy(&f, &v, 4); return f;
}
__device__ __forceinline__ unsigned short f2u(float f) {
  bf16 b = __float2bfloat16(f);
  unsigned short u; __builtin_memcpy(&u, &b, 2); return u;
}

// ---------------- prep kernels ----------------
__global__ void k_zero4k(float* p) {            // grid 4 x 256 -> 4KB zero page
  p[blockIdx.x * 256 + threadIdx.x] = 0.f;
}

__global__ void k_castf2b(const float* __restrict__ s, bf16* __restrict__ d, int n) {
  int i = blockIdx.x * 256 + threadIdx.x;
  if (i < n) d[i] = __float2bfloat16(s[i]);
}

__global__ void k_copyf(const float* __restrict__ s, float* __restrict__ d, int n) {
  int i = blockIdx.x * 256 + threadIdx.x;
  if (i < n) d[i] = s[i];
}

// conv weight permute: OIHW fp32 -> [O][tap][I] bf16
__global__ void k_permconv(const float* __restrict__ w, bf16* __restrict__ o, int I) {
  int idx = blockIdx.x * 256 + threadIdx.x;
  int tot = 256 * 9 * I;
  if (idx >= tot) return;
  int i   = idx % I;
  int rem = idx / I;
  int tap = rem % 9;
  int oc  = rem / 9;
  o[idx] = __float2bfloat16(w[(oc * I + i) * 9 + tap]);
}

// NCHW fp32 -> NHWC bf16 (32x32 LDS tile transpose)
__global__ void k_tohwc(const float* __restrict__ src, bf16* __restrict__ dst, int C) {
  int bh = blockIdx.x;                 // b*H + h
  int w0 = blockIdx.y * 32;
  int c0 = blockIdx.z * 32;
  int b = bh / Himg, h = bh % Himg;
  __shared__ float tile[32][33];
  int tid = threadIdx.x;
  int x = tid & 31, y = tid >> 5;      // y in 0..7
  const float* sp = src + (size_t)b * C * HWimg + (size_t)h * Wimg;
#pragma unroll
  for (int p = 0; p < 4; ++p) {
    int cl = y + p * 8;
    tile[cl][x] = sp[(size_t)(c0 + cl) * HWimg + w0 + x];
  }
  __syncthreads();
#pragma unroll
  for (int p = 0; p < 4; ++p) {
    int wl = y + p * 8;
    dst[((size_t)bh * Wimg + w0 + wl) * C + c0 + x] = __float2bfloat16(tile[x][wl]);
  }
}

// NHWC fp32 -> NCHW fp32 (final output)
__global__ void k_tochw(const float* __restrict__ src, float* __restrict__ dst) {
  int bh = blockIdx.x, w0 = blockIdx.y * 32, c0 = blockIdx.z * 32;
  int b = bh >> 8, h = bh & 255;
  __shared__ float tile[32][33];
  int tid = threadIdx.x, x = tid & 31, y = tid >> 5;
  const float* sp = src + (size_t)bh * Wimg * 256;
#pragma unroll
  for (int p = 0; p < 4; ++p) {
    int wl = y + p * 8;
    tile[wl][x] = sp[(size_t)(w0 + wl) * 256 + c0 + x];
  }
  __syncthreads();
#pragma unroll
  for (int p = 0; p < 4; ++p) {
    int cl = y + p * 8;
    dst[(((size_t)b * 256 + c0 + cl) * Himg + h) * Wimg + w0 + x] = tile[x][cl];
  }
}

// ---------------- fused implicit-GEMM / conv kernel ----------------
// A: [T][CIN] bf16 token-major (NHWC). BT: [Ntot][TAPS*CIN] bf16.
// EPI 0: outb[t*ldo+col] = bf16(acc+bias)
// EPI 1: gate[t*768+col] = bf16(sigmoid(acc+bias) * gate[t*768+col])   (col < 512)
// EPI 2: outf[t*256+col] = acc + bias + float(ident[t*256+col])
template <int CIN, int TAPS, int EPI>
__global__ void __launch_bounds__(256, 2)
k_gemm(const bf16* __restrict__ Ain, const bf16* __restrict__ BT,
       const float* __restrict__ bias,
       bf16* __restrict__ outb, int ldo,
       float* __restrict__ outf, const bf16* __restrict__ ident,
       bf16* __restrict__ gate, const bf16* __restrict__ zp)
{
  constexpr int KTOT = TAPS * CIN;
  const int t0 = blockIdx.x * 128;
  const int n0 = blockIdx.y * 128;
  const int tid = threadIdx.x;
  const int wave = tid >> 6, lane = tid & 63;
  const int seg = lane & 3;
  const int rr  = lane >> 2;           // 0..15

  __shared__ bf16 sA[128 * 32];
  __shared__ bf16 sB[128 * 32];

  f32x4 acc[4][4] = {};

  const int wr = wave >> 1, wc = wave & 1;
  const int fr = lane & 15, fq = lane >> 4;

  for (int k0 = 0; k0 < KTOT; k0 += 32) {
    const int tap = k0 / CIN;
    const int c0  = k0 - tap * CIN;
    const int dy  = tap / 3 - 1, dx = tap % 3 - 1;
#pragma unroll
    for (int i = 0; i < 2; ++i) {
      const int r = wave * 32 + i * 16 + rr;
      const int t = t0 + r;
      const bf16* src;
      if (TAPS == 1) {
        src = Ain + (size_t)t * CIN + c0 + seg * 8;
      } else {
        const int h = (t >> 8) & 255, w = t & 255;
        const int hh = h + dy, ww = w + dx;
        const bool valid = ((unsigned)hh < 256u) && ((unsigned)ww < 256u);
        const long gi = (long)t + dy * Wimg + dx;
        src = valid ? (Ain + gi * CIN + c0 + seg * 8) : (zp + seg * 8);
      }
      gld16(sA + (wave * 32 + i * 16) * 32, src);
    }
#pragma unroll
    for (int i = 0; i < 2; ++i) {
      const int r = wave * 32 + i * 16 + rr;
      const bf16* src = BT + (size_t)(n0 + r) * KTOT + k0 + seg * 8;
      gld16(sB + (wave * 32 + i * 16) * 32, src);
    }
    __syncthreads();
    s16x8 af[4], bfrag[4];
#pragma unroll
    for (int m = 0; m < 4; ++m)
      af[m] = *(const s16x8*)(sA + (wr * 64 + m * 16 + fr) * 32 + fq * 8);
#pragma unroll
    for (int n = 0; n < 4; ++n)
      bfrag[n] = *(const s16x8*)(sB + (wc * 64 + n * 16 + fr) * 32 + fq * 8);
#pragma unroll
    for (int m = 0; m < 4; ++m)
#pragma unroll
      for (int n = 0; n < 4; ++n)
        acc[m][n] = __builtin_amdgcn_mfma_f32_16x16x32_bf16(af[m], bfrag[n], acc[m][n], 0, 0, 0);
    __syncthreads();
  }

#pragma unroll
  for (int m = 0; m < 4; ++m) {
#pragma unroll
    for (int n = 0; n < 4; ++n) {
      const int col = n0 + wc * 64 + n * 16 + fr;
#pragma unroll
      for (int j = 0; j < 4; ++j) {
        const int row = wr * 64 + m * 16 + fq * 4 + j;
        const size_t t = (size_t)t0 + row;
        float v = acc[m][n][j] + bias[col];
        if (EPI == 0) {
          outb[t * ldo + col] = __float2bfloat16(v);
        } else if (EPI == 1) {
          const float s = 1.f / (1.f + __expf(-v));
          bf16* p = gate + t * 768 + col;
          *p = __float2bfloat16(s * __bfloat162float(*p));
        } else {
          v += __bfloat162float(ident[t * 256 + col]);
          outf[t * 256 + col] = v;
        }
      }
    }
  }
}

// ---------------- window attention (VALU baseline) ----------------
// qkv: [T][768] bf16 (0:256 q_g, 256:512 k_g, 512:768 v). out: [T][256] bf16.
__global__ void __launch_bounds__(64, 2) k_attn(const bf16* __restrict__ qkv,
                                                bf16* __restrict__ out) {
  __shared__ float Kl[64][32];
  __shared__ float Vl[64][32];
  const int head = blockIdx.x & 7;
  const int wi   = blockIdx.x >> 3;
  const int b = wi >> 10, rem = wi & 1023, wh = rem >> 5, ww = rem & 31;
  const int n = threadIdx.x;
  const int h = wh * 8 + (n >> 3), w = ww * 8 + (n & 7);
  const size_t t = (size_t)b * HWimg + (size_t)h * Wimg + w;
  const bf16* base = qkv + t * 768;

  float q[32];
#pragma unroll
  for (int j = 0; j < 4; ++j) {
    s16x8 v = *(const s16x8*)(base + head * 32 + j * 8);
#pragma unroll
    for (int e = 0; e < 8; ++e) q[j * 8 + e] = b2f((unsigned short)v[e]);
  }
#pragma unroll
  for (int j = 0; j < 4; ++j) {
    s16x8 kv = *(const s16x8*)(base + 256 + head * 32 + j * 8);
    s16x8 vv = *(const s16x8*)(base + 512 + head * 32 + j * 8);
#pragma unroll
    for (int e = 0; e < 8; ++e) {
      Kl[n][j * 8 + e] = b2f((unsigned short)kv[e]);
      Vl[n][j * 8 + e] = b2f((unsigned short)vv[e]);
    }
  }
  __syncthreads();

  const float scale = 0.17677669529663688f;   // 1/sqrt(32)
  float s[64];
  float mx = -1e30f;
#pragma unroll
  for (int m = 0; m < 64; ++m) {
    float a = 0.f;
#pragma unroll
    for (int d = 0; d < 32; d += 4) {
      const f32x4 kk = *(const f32x4*)&Kl[m][d];
      a += q[d] * kk.x + q[d + 1] * kk.y + q[d + 2] * kk.z + q[d + 3] * kk.w;
    }
    a *= scale;
    s[m] = a;
    mx = fmaxf(mx, a);
  }
  float sum = 0.f;
#pragma unroll
  for (int m = 0; m < 64; ++m) { float e = __expf(s[m] - mx); s[m] = e; sum += e; }
  const float inv = 1.f / sum;
  float o[32];
#pragma unroll
  for (int d = 0; d < 32; ++d) o[d] = 0.f;
#pragma unroll
  for (int m = 0; m < 64; ++m) {
    const float p = s[m];
#pragma unroll
    for (int d = 0; d < 32; d += 4) {
      const f32x4 vv = *(const f32x4*)&Vl[m][d];
      o[d] += p * vv.x; o[d + 1] += p * vv.y; o[d + 2] += p * vv.z; o[d + 3] += p * vv.w;
    }
  }
  bf16* op = out + t * 256 + head * 32;
#pragma unroll
  for (int j = 0; j < 4; ++j) {
    s16x8 ov;
#pragma unroll
    for (int e = 0; e < 8; ++e) ov[e] = (short)f2u(o[j * 8 + e] * inv);
    *(s16x8*)(op + j * 8) = ov;
  }
}

// ---------------- host ----------------
extern "C" void kernel_launch(void* const* d_in, const int* in_sizes, int n_in,
                              void* d_out, int out_size, void* d_ws, size_t ws_size,
                              hipStream_t stream) {
  const float* xmap    = (const float*)d_in[0];
  const float* xfeat   = (const float*)d_in[1];
  const float* cmap_w  = (const float*)d_in[2];
  const float* cmap_b  = (const float*)d_in[3];
  const float* cfeat_w = (const float*)d_in[4];
  const float* cfeat_b = (const float*)d_in[5];
  const float* qxmap_w = (const float*)d_in[6];
  const float* qxmap_b = (const float*)d_in[7];
  const float* kxmap_w = (const float*)d_in[8];
  const float* kxmap_b = (const float*)d_in[9];
  const float* vxmap_w = (const float*)d_in[10];
  const float* vxmap_b = (const float*)d_in[11];
  const float* qxfeat_w = (const float*)d_in[12];
  const float* qxfeat_b = (const float*)d_in[13];
  const float* kxfeat_w = (const float*)d_in[14];
  const float* kxfeat_b = (const float*)d_in[15];
  const float* proj_w  = (const float*)d_in[16];
  const float* proj_b  = (const float*)d_in[17];
  const float* cout_w  = (const float*)d_in[18];
  const float* cout_b  = (const float*)d_in[19];

  uint8_t* ws = (uint8_t*)d_ws;
  size_t off = 0;
  auto alloc = [&](size_t bytes) -> void* {
    void* p = ws + off;
    off += (bytes + 255) & ~(size_t)255;
    return p;
  };
  float* zp       = (float*)alloc(4096);
  bf16* cmap_wT   = (bf16*)alloc((size_t)2304 * 256 * 2);
  bf16* cout_wT   = (bf16*)alloc((size_t)2304 * 256 * 2);
  bf16* cfeat_wT  = (bf16*)alloc((size_t)288 * 256 * 2);
  bf16* lin_qkv_wT= (bf16*)alloc((size_t)768 * 256 * 2);
  bf16* lin_f_wT  = (bf16*)alloc((size_t)512 * 256 * 2);
  bf16* proj_wT   = (bf16*)alloc((size_t)256 * 256 * 2);
  float* bias_qkv = (float*)alloc(768 * 4);
  float* bias_f   = (float*)alloc(512 * 4);
  bf16* xm_nhwc   = (bf16*)alloc((size_t)Ttok * 256 * 2);
  bf16* xf_nhwc   = (bf16*)alloc((size_t)Ttok * 32 * 2);
  bf16* xc        = (bf16*)alloc((size_t)Ttok * 256 * 2);
  bf16* fc        = (bf16*)alloc((size_t)Ttok * 256 * 2);
  bf16* qkv       = (bf16*)alloc((size_t)Ttok * 768 * 2);
  bf16* attn_out  = xm_nhwc;          // reuse (xm_nhwc dead after conv cmap)
  bf16* proj_out  = fc;               // reuse (fc dead after gating GEMM)
  float* convout  = (float*)qkv;      // reuse (qkv dead after attention+proj)
  bf16* zpb = (bf16*)zp;

  k_zero4k<<<4, 256, 0, stream>>>(zp);
  k_permconv<<<(256 * 9 * 256 + 255) / 256, 256, 0, stream>>>(cmap_w, cmap_wT, 256);
  k_permconv<<<(256 * 9 * 256 + 255) / 256, 256, 0, stream>>>(cout_w, cout_wT, 256);
  k_permconv<<<(256 * 9 * 32 + 255) / 256, 256, 0, stream>>>(cfeat_w, cfeat_wT, 32);
  k_castf2b<<<256, 256, 0, stream>>>(qxmap_w, lin_qkv_wT, 65536);
  k_castf2b<<<256, 256, 0, stream>>>(kxmap_w, lin_qkv_wT + 65536, 65536);
  k_castf2b<<<256, 256, 0, stream>>>(vxmap_w, lin_qkv_wT + 131072, 65536);
  k_castf2b<<<256, 256, 0, stream>>>(qxfeat_w, lin_f_wT, 65536);
  k_castf2b<<<256, 256, 0, stream>>>(kxfeat_w, lin_f_wT + 65536, 65536);
  k_castf2b<<<256, 256, 0, stream>>>(proj_w, proj_wT, 65536);
  k_copyf<<<1, 256, 0, stream>>>(qxmap_b, bias_qkv, 256);
  k_copyf<<<1, 256, 0, stream>>>(kxmap_b, bias_qkv + 256, 256);
  k_copyf<<<1, 256, 0, stream>>>(vxmap_b, bias_qkv + 512, 256);
  k_copyf<<<1, 256, 0, stream>>>(qxfeat_b, bias_f, 256);
  k_copyf<<<1, 256, 0, stream>>>(kxfeat_b, bias_f + 256, 256);

  k_tohwc<<<dim3(Bimg * Himg, Wimg / 32, 256 / 32), 256, 0, stream>>>(xmap, xm_nhwc, 256);
  k_tohwc<<<dim3(Bimg * Himg, Wimg / 32, 1), 256, 0, stream>>>(xfeat, xf_nhwc, 32);

  dim3 blk(256);
  // conv cmap -> xc (identity, bf16)
  k_gemm<256, 9, 0><<<dim3(Ttok / 128, 2), blk, 0, stream>>>(
      xm_nhwc, cmap_wT, cmap_b, xc, 256, nullptr, nullptr, nullptr, zpb);
  // conv cfeat -> fc
  k_gemm<32, 9, 0><<<dim3(Ttok / 128, 2), blk, 0, stream>>>(
      xf_nhwc, cfeat_wT, cfeat_b, fc, 256, nullptr, nullptr, nullptr, zpb);
  // qm|km|vm GEMM -> qkv
  k_gemm<256, 1, 0><<<dim3(Ttok / 128, 6), blk, 0, stream>>>(
      xc, lin_qkv_wT, bias_qkv, qkv, 768, nullptr, nullptr, nullptr, zpb);
  // qf|kf GEMM + sigmoid gating in-place on qkv
  k_gemm<256, 1, 1><<<dim3(Ttok / 128, 4), blk, 0, stream>>>(
      fc, lin_f_wT, bias_f, nullptr, 0, nullptr, nullptr, qkv, zpb);
  // window attention
  k_attn<<<dim3(4096 * 8), dim3(64), 0, stream>>>(qkv, attn_out);
  // proj GEMM
  k_gemm<256, 1, 0><<<dim3(Ttok / 128, 2), blk, 0, stream>>>(
      attn_out, proj_wT, proj_b, proj_out, 256, nullptr, nullptr, nullptr, zpb);
  // conv cout + bias + identity -> convout (NHWC fp32)
  k_gemm<256, 9, 2><<<dim3(Ttok / 128, 2), blk, 0, stream>>>(
      proj_out, cout_wT, cout_b, nullptr, 0, convout, xc, nullptr, zpb);
  // NHWC -> NCHW final
  k_tochw<<<dim3(Bimg * Himg, Wimg / 32, 256 / 32), 256, 0, stream>>>(convout, (float*)d_out);
}